// Round 8
// baseline (224.530 us; speedup 1.0000x reference)
//
#include <hip/hip_runtime.h>
#include <math.h>

// EvidNets fused, MFMA bf16x2, barrier-free + software-pipelined chunks.
//   A_c(b) = prod_k (1 - s_kb * (1 - U_kc)),  N(b) = prod_k (1 - s_kb)
//   out[b][c<20] = (A_c - N)/K,  out[b][20] = N/K,  K = sum_c A_c - 19*N
//   s_kb = alphap_k * exp(-gamma_k^2 * (0.5*(|W_k|^2 + |x_b|^2) - W_k.x_b))
// GEMM W@X^T via v_mfma_f32_32x32x16_bf16, hi/lo bf16 split, 3 passes kept in
// THREE independent acc chains (R7: single chained acc = dependent-latency
// bound). B-ring / 1-U slice / params for chunk k+1 prefetched under chunk
// k's epilogue+combine VALU. No __syncthreads in the chunk loop.
// NOTE: plain __launch_bounds__(256) — (256,2) caused scratch spill (R4/R5).

#define NBATCH 16384
#define ND     256
#define NP     512
#define NCLS   20
#define OC     21

typedef short  short8  __attribute__((ext_vector_type(8)));
typedef short  short4v __attribute__((ext_vector_type(4)));
typedef unsigned short ushort8 __attribute__((ext_vector_type(8)));
typedef float  f32x16  __attribute__((ext_vector_type(16)));

// ---- workspace layout (bytes) ----
#define OFF_PWH 0u
#define OFF_PWL 262144u
#define OFF_VS  524288u                 // float VS[21][512] = 1-U (row 20 = 1)
#define OFF_WQ  (OFF_VS + 43008u)
#define OFF_AP  (OFF_WQ + 2048u)
#define OFF_G2  (OFF_AP + 2048u)
#define WS_NEED ((size_t)(OFF_G2 + 2048u))

__device__ __forceinline__ unsigned short f2bf_rn(float f) {
  unsigned int u = __float_as_uint(f);
  unsigned int r = (u + 0x7FFFu + ((u >> 16) & 1u)) >> 16;   // RNE (finite inputs)
  return (unsigned short)r;
}
__device__ __forceinline__ float bf2f(unsigned short h) {
  return __uint_as_float(((unsigned int)h) << 16);
}

// Combined prep: blocks 0..63 pack W[512][256] -> MFMA B-fragment order hi/lo
// bf16 + row sum-squares; blocks 64..65 build VS/AP/G2 tables.
// frag elem (tile,step,lane,j) = src[tile*32+(lane&31)][step*16+8*(lane>>5)+j]
__global__ __launch_bounds__(256)
void prep(const float* __restrict__ Wsrc, const float* __restrict__ BETA,
          const float* __restrict__ alpha, const float* __restrict__ gamma,
          unsigned short* __restrict__ dh, unsigned short* __restrict__ dl,
          float* __restrict__ sq, float* __restrict__ VS,
          float* __restrict__ AP, float* __restrict__ G2)
{
  const int bid = blockIdx.x;
  if (bid < 64) {                      // ---- pack W ----
    const int tid = bid * 256 + threadIdx.x;
    const int row = tid >> 5, seg = tid & 31;
    const float4* s4 = (const float4*)(Wsrc + (size_t)row * ND + seg * 8);
    const float4 a = s4[0], b = s4[1];
    const float v[8] = {a.x, a.y, a.z, a.w, b.x, b.y, b.z, b.w};
    ushort8 hv, lv;
    float ssq = 0.f;
    #pragma unroll
    for (int j = 0; j < 8; ++j) {
      ssq = fmaf(v[j], v[j], ssq);
      const unsigned short hh = f2bf_rn(v[j]);
      hv[j] = hh;
      lv[j] = f2bf_rn(v[j] - bf2f(hh));
    }
    const int tile = row >> 5, m = row & 31, step = seg >> 1, r = seg & 1;
    const size_t cidx = (size_t)(tile * 16 + step) * 64 + m + 32 * r;
    *(ushort8*)(dh + cidx * 8) = hv;
    *(ushort8*)(dl + cidx * 8) = lv;
    #pragma unroll
    for (int off = 1; off < 32; off <<= 1) ssq += __shfl_xor(ssq, off, 64);
    if (seg == 0) sq[row] = ssq;
  } else {                             // ---- scalar tables ----
    const int k = (bid - 64) * 256 + threadIdx.x;
    if (k >= NP) return;
    float bv[NCLS], bs = 0.f;
    #pragma unroll
    for (int c = 0; c < NCLS; ++c) { bv[c] = BETA[k * NCLS + c]; bs = fmaf(bv[c], bv[c], bs); }
    const float binv = 1.f / bs;
    #pragma unroll
    for (int c = 0; c < NCLS; ++c) VS[c * NP + k] = 1.f - bv[c] * bv[c] * binv;
    VS[NCLS * NP + k] = 1.f;
    AP[k] = 0.99f / (1.f + __expf(-alpha[k]));
    const float g = gamma[k];
    G2[k] = g * g;
  }
}

// Main kernel: 512 blocks x 256 threads, 32 samples/block. Wave w owns the
// 32x32 (sample x proto) tile for protos [chunk*128 + w*32, +32), 4 chunks.
__global__ __launch_bounds__(256)
void evid_main(const float* __restrict__ X,
               const unsigned short* __restrict__ PWH, const unsigned short* __restrict__ PWL,
               const float* __restrict__ VS, const float* __restrict__ WQ,
               const float* __restrict__ AP, const float* __restrict__ G2,
               float* __restrict__ OUT)
{
  __shared__ __align__(16) short Ah[8192], Al[8192];   // shared A-frags (read-only post-barrier)
  __shared__ __align__(16) float sst[4][32 * 36];      // per-wave s[b][proto_local], pad 36
  __shared__ __align__(16) float vsw[2][4][704];       // parity x wave: 1-U slice [c*32+kk]
  __shared__ float xqs[32];

  const int t    = threadIdx.x;
  const int lane = t & 63, wave = t >> 6;
  const int tile = blockIdx.x;
  const int bbase = tile * 32;
  const int pl    = lane & 31;          // proto lane within wave tile
  const int ipart = (lane >> 5) & 1;    // in-wave k-half for combine

  // ---- prologue prefetch for chunk 0 (in flight during X staging) ----
  float v0reg[11];
  #pragma unroll
  for (int j = 0; j < 11; ++j) {
    const int i = lane + j * 64;
    v0reg[j] = VS[(i >> 5) * NP + wave * 32 + (i & 31)];
  }
  float wqk = WQ[wave * 32 + pl];
  float apk = AP[wave * 32 + pl];
  float g2k = G2[wave * 32 + pl];

  const short8* bH = (const short8*)PWH + (size_t)wave * 1024 + lane;
  const short8* bL = (const short8*)PWL + (size_t)wave * 1024 + lane;
  short8 wbh[4], wbl[4];
  #pragma unroll
  for (int p = 0; p < 4; ++p) { wbh[p] = bH[p * 64]; wbl[p] = bL[p * 64]; }

  // ---- stage: convert X rows f32 -> hi/lo bf16 fragments in LDS ----
  {
    const int r  = t >> 3;                // sample row 0..31 (8 consecutive lanes/row)
    const int sg = t & 7;                 // float4 slot
    const float* xrow = X + (size_t)(bbase + r) * ND;
    float ssq = 0.f;
    #pragma unroll
    for (int it = 0; it < 8; ++it) {
      const int c0 = it * 32 + sg * 4;
      const float4 v = *(const float4*)(xrow + c0);
      const float vv[4] = {v.x, v.y, v.z, v.w};
      short4v h4, l4;
      #pragma unroll
      for (int j = 0; j < 4; ++j) {
        ssq = fmaf(vv[j], vv[j], ssq);
        const unsigned short hh = f2bf_rn(vv[j]);
        h4[j] = (short)hh;
        l4[j] = (short)f2bf_rn(vv[j] - bf2f(hh));
      }
      const int step = c0 >> 4, half = (c0 >> 3) & 1, j0 = c0 & 7;
      const int base = (step * 64 + (r + 32 * half)) * 8 + j0;
      *(short4v*)&Ah[base] = h4;
      *(short4v*)&Al[base] = l4;
    }
    ssq += __shfl_xor(ssq, 1, 64);
    ssq += __shfl_xor(ssq, 2, 64);
    ssq += __shfl_xor(ssq, 4, 64);      // reduced over the 8 lanes of this row
    if (sg == 0) xqs[r] = ssq;
  }

  // park chunk-0 vs slice into parity-0 buffer
  #pragma unroll
  for (int j = 0; j < 11; ++j) vsw[0][wave][lane + j * 64] = v0reg[j];

  float Ap[OC];
  #pragma unroll
  for (int c = 0; c < OC; ++c) Ap[c] = 1.0f;

  __syncthreads();    // the ONLY barrier before the endgame: Ah/Al/xqs final

  #pragma unroll 1
  for (int chunk = 0; chunk < 4; ++chunk) {
    const int par = chunk & 1;

    // MFMA: 32x32 tile over K=256; THREE independent acc chains (hh, hl, lh)
    f32x16 accA, accB, accC;
    #pragma unroll
    for (int i = 0; i < 16; ++i) { accA[i] = 0.f; accB[i] = 0.f; accC[i] = 0.f; }
    const short8* aH = (const short8*)Ah + lane;
    const short8* aL = (const short8*)Al + lane;

    #pragma unroll
    for (int step = 0; step < 16; ++step) {
      const short8 ah = aH[step * 64], al = aL[step * 64];
      const short8 bh = wbh[step & 3], bl = wbl[step & 3];
      if (step < 12) {                 // refill ring slot 4 steps ahead
        wbh[step & 3] = bH[(step + 4) * 64];
        wbl[step & 3] = bL[(step + 4) * 64];
      }
      accA = __builtin_amdgcn_mfma_f32_32x32x16_bf16(ah, bh, accA, 0, 0, 0);
      accB = __builtin_amdgcn_mfma_f32_32x32x16_bf16(ah, bl, accB, 0, 0, 0);
      accC = __builtin_amdgcn_mfma_f32_32x32x16_bf16(al, bh, accC, 0, 0, 0);
    }

    // ---- prefetch chunk+1 under the epilogue/combine VALU ----
    float vnext[11], nwq = wqk, nap = apk, ng2 = g2k;
    if (chunk < 3) {
      const int k0n = (chunk + 1) * 128 + wave * 32;
      #pragma unroll
      for (int j = 0; j < 11; ++j) {
        const int i = lane + j * 64;
        vnext[j] = VS[(i >> 5) * NP + k0n + (i & 31)];
      }
      nwq = WQ[k0n + pl]; nap = AP[k0n + pl]; ng2 = G2[k0n + pl];
      bH += 4096; bL += 4096;          // advance 4 tiles to next chunk
      #pragma unroll
      for (int p = 0; p < 4; ++p) { wbh[p] = bH[p * 64]; wbl[p] = bL[p * 64]; }
    }

    // epilogue: s = alphap * exp(-g2 * (0.5*(wq+xq) - dot)), TRANSPOSED write
    // C/D layout: col(n)=lane&31 (proto), row(m)=(reg&3)+8*(reg>>2)+4*(lane>>5)
    {
      const int rb = 4 * (lane >> 5);
      #pragma unroll
      for (int rg = 0; rg < 16; ++rg) {
        const int   m  = (rg & 3) + 8 * (rg >> 2) + rb;
        const float dv = 0.5f * (wqk + xqs[m]) - (accA[rg] + accB[rg] + accC[rg]);
        sst[wave][m * 36 + pl] = apk * __expf(-g2k * dv);
      }
    }
    // same-wave LDS RAW: compiler inserts lgkmcnt wait; no barrier needed.

    // combine: thread (b=pl, ipart) folds its 16 k's into Ap[21], float4 reads
    {
      const float* sbase = &sst[wave][pl * 36 + ipart * 16];
      const float4 s0 = *(const float4*)(sbase + 0);
      const float4 s1 = *(const float4*)(sbase + 4);
      const float4 s2 = *(const float4*)(sbase + 8);
      const float4 s3 = *(const float4*)(sbase + 12);
      const float* vbase = &vsw[par][wave][ipart * 16];
      #pragma unroll
      for (int c = 0; c < OC; ++c) {
        const float4 v0 = *(const float4*)(vbase + c * 32 + 0);
        const float4 v1 = *(const float4*)(vbase + c * 32 + 4);
        const float4 v2 = *(const float4*)(vbase + c * 32 + 8);
        const float4 v3 = *(const float4*)(vbase + c * 32 + 12);
        const float p0 = fmaf(-s0.x, v0.x, 1.f) * fmaf(-s0.y, v0.y, 1.f)
                       * fmaf(-s0.z, v0.z, 1.f) * fmaf(-s0.w, v0.w, 1.f);
        const float p1 = fmaf(-s1.x, v1.x, 1.f) * fmaf(-s1.y, v1.y, 1.f)
                       * fmaf(-s1.z, v1.z, 1.f) * fmaf(-s1.w, v1.w, 1.f);
        const float p2 = fmaf(-s2.x, v2.x, 1.f) * fmaf(-s2.y, v2.y, 1.f)
                       * fmaf(-s2.z, v2.z, 1.f) * fmaf(-s2.w, v2.w, 1.f);
        const float p3 = fmaf(-s3.x, v3.x, 1.f) * fmaf(-s3.y, v3.y, 1.f)
                       * fmaf(-s3.z, v3.z, 1.f) * fmaf(-s3.w, v3.w, 1.f);
        Ap[c] *= (p0 * p1) * (p2 * p3);
      }
    }

    // park chunk+1's vs slice + params (writes complete under next MFMA)
    if (chunk < 3) {
      #pragma unroll
      for (int j = 0; j < 11; ++j) vsw[par ^ 1][wave][lane + j * 64] = vnext[j];
      wqk = nwq; apk = nap; g2k = ng2;
    }
  }

  // ---- endgame: reduce 8 partial products per (b,c), normalize, store ----
  float* S = &sst[0][0];
  const int cb = t & 31, part = t >> 5;
  __syncthreads();
  if (part >= 4) {
    #pragma unroll
    for (int c = 0; c < OC; ++c) S[((part - 4) * OC + c) * 33 + cb] = Ap[c];
  }
  __syncthreads();
  if (part < 4) {
    #pragma unroll
    for (int c = 0; c < OC; ++c) Ap[c] *= S[(part * OC + c) * 33 + cb];
  }
  __syncthreads();
  if (part >= 2 && part < 4) {
    #pragma unroll
    for (int c = 0; c < OC; ++c) S[((part - 2) * OC + c) * 33 + cb] = Ap[c];
  }
  __syncthreads();
  if (part < 2) {
    #pragma unroll
    for (int c = 0; c < OC; ++c) Ap[c] *= S[(part * OC + c) * 33 + cb];
  }
  __syncthreads();
  if (part == 1) {
    #pragma unroll
    for (int c = 0; c < OC; ++c) S[c * 33 + cb] = Ap[c];
  }
  __syncthreads();
  if (part == 0) {
    #pragma unroll
    for (int c = 0; c < OC; ++c) Ap[c] *= S[c * 33 + cb];
    const float Nv = Ap[NCLS];
    float Ks = Nv;
    #pragma unroll
    for (int c = 0; c < NCLS; ++c) Ks += Ap[c] - Nv;
    const float invk = 1.0f / Ks;
    #pragma unroll
    for (int c = 0; c < NCLS; ++c) S[c * 33 + cb] = (Ap[c] - Nv) * invk;
    S[NCLS * 33 + cb] = Nv * invk;
  }
  __syncthreads();
  for (int idx = t; idx < 32 * OC; idx += 256) {
    const int b = idx / OC, c = idx - b * OC;
    OUT[(size_t)tile * 32 * OC + idx] = S[c * 33 + b];
  }
}

// ---------------- fallback (verified f32 path, used if ws too small) ----------------
#define TBF 64
#define TKF 64
#define DSL 64
#define LDX 68

__device__ __forceinline__ void fma4(const float4 a, const float4 b, float& d) {
  d = fmaf(a.x, b.x, d); d = fmaf(a.y, b.y, d);
  d = fmaf(a.z, b.z, d); d = fmaf(a.w, b.w, d);
}

__global__ __launch_bounds__(256)
void evid_fused(const float* __restrict__ X, const float* __restrict__ Wm,
                const float* __restrict__ BETA, const float* __restrict__ ALPHA,
                const float* __restrict__ GAMMA, float* __restrict__ OUT)
{
  __shared__ __align__(16) float xs[DSL][LDX], wsh[DSL][LDX], ssf[TKF][LDX], vs[OC][LDX];
  __shared__ float xq[TBF], wq[TKF], apch[TKF], g2ch[TKF];
  __shared__ float redx[4][TBF], redw[4][TKF];
  const int t = threadIdx.x, bbase = blockIdx.x * TBF;
  const int tb = t & 15, tk = t >> 4, srow = t >> 4, sdq = t & 15;
  const int cbf = t & 63, part = t >> 6;
  float Ap[OC];
  #pragma unroll
  for (int c = 0; c < OC; ++c) Ap[c] = 1.0f;
  float xqacc = 0.0f;
  for (int chunk = 0; chunk < 8; ++chunk) {
    const int k0 = chunk * TKF;
    __syncthreads();
    if (t < TKF) {
      const int k = k0 + t;
      float bsum = 0.0f;
      #pragma unroll
      for (int c = 0; c < NCLS; ++c) { const float bv = BETA[k*NCLS+c]; bsum = fmaf(bv, bv, bsum); }
      const float binv = 1.0f / bsum;
      #pragma unroll
      for (int c = 0; c < NCLS; ++c) { const float bv = BETA[k*NCLS+c]; vs[c][t] = 1.0f - bv*bv*binv; }
      vs[NCLS][t] = 1.0f;
      apch[t] = 0.99f / (1.0f + expf(-ALPHA[k]));
      const float gv = GAMMA[k]; g2ch[t] = gv * gv;
    }
    float acc[4][4] = {};
    float wqacc = 0.0f;
    for (int sl = 0; sl < 4; ++sl) {
      const int d0 = sl * DSL;
      __syncthreads();
      #pragma unroll
      for (int p = 0; p < 4; ++p) {
        const int r = srow + 16 * p;
        *(float4*)&xs [r][4*sdq] = *(const float4*)&X [(size_t)(bbase + r)*ND + d0 + 4*sdq];
        *(float4*)&wsh[r][4*sdq] = *(const float4*)&Wm[(size_t)(k0    + r)*ND + d0 + 4*sdq];
      }
      __syncthreads();
      #pragma unroll
      for (int m = 0; m < 4; ++m) {
        const float4 v = *(const float4*)&wsh[cbf][part*16 + 4*m];
        wqacc = fmaf(v.x,v.x, fmaf(v.y,v.y, fmaf(v.z,v.z, fmaf(v.w,v.w, wqacc))));
      }
      if (chunk == 0) {
        #pragma unroll
        for (int m = 0; m < 4; ++m) {
          const float4 v = *(const float4*)&xs[cbf][part*16 + 4*m];
          xqacc = fmaf(v.x,v.x, fmaf(v.y,v.y, fmaf(v.z,v.z, fmaf(v.w,v.w, xqacc))));
        }
      }
      #pragma unroll
      for (int dq = 0; dq < 16; ++dq) {
        const float4 xa0 = *(const float4*)&xs [tb +  0][4*dq];
        const float4 xa1 = *(const float4*)&xs [tb + 16][4*dq];
        const float4 xa2 = *(const float4*)&xs [tb + 32][4*dq];
        const float4 xa3 = *(const float4*)&xs [tb + 48][4*dq];
        const float4 wb0 = *(const float4*)&wsh[tk +  0][4*dq];
        const float4 wb1 = *(const float4*)&wsh[tk + 16][4*dq];
        const float4 wb2 = *(const float4*)&wsh[tk + 32][4*dq];
        const float4 wb3 = *(const float4*)&wsh[tk + 48][4*dq];
        fma4(xa0, wb0, acc[0][0]); fma4(xa0, wb1, acc[0][1]); fma4(xa0, wb2, acc[0][2]); fma4(xa0, wb3, acc[0][3]);
        fma4(xa1, wb0, acc[1][0]); fma4(xa1, wb1, acc[1][1]); fma4(xa1, wb2, acc[1][2]); fma4(xa1, wb3, acc[1][3]);
        fma4(xa2, wb0, acc[2][0]); fma4(xa2, wb1, acc[2][1]); fma4(xa2, wb2, acc[2][2]); fma4(xa2, wb3, acc[2][3]);
        fma4(xa3, wb0, acc[3][0]); fma4(xa3, wb1, acc[3][1]); fma4(xa3, wb2, acc[3][2]); fma4(xa3, wb3, acc[3][3]);
      }
    }
    redw[part][cbf] = wqacc;
    if (chunk == 0) redx[part][cbf] = xqacc;
    __syncthreads();
    if (t < TKF) {
      wq[t] = redw[0][t] + redw[1][t] + redw[2][t] + redw[3][t];
      if (chunk == 0) xq[t] = redx[0][t] + redx[1][t] + redx[2][t] + redx[3][t];
    }
    __syncthreads();
    #pragma unroll
    for (int j = 0; j < 4; ++j) {
      const int kj = tk + 16 * j;
      const float wqk = wq[kj], ap = apch[kj], g2 = g2ch[kj];
      #pragma unroll
      for (int i = 0; i < 4; ++i) {
        const int bi = tb + 16 * i;
        ssf[kj][bi] = ap * expf(-g2 * (0.5f*(wqk + xq[bi]) - acc[i][j]));
      }
    }
    __syncthreads();
    {
      float sv[16];
      #pragma unroll
      for (int m = 0; m < 16; ++m) sv[m] = ssf[16*part + m][cbf];
      #pragma unroll
      for (int c = 0; c < OC; ++c) {
        float a = Ap[c];
        #pragma unroll
        for (int mq = 0; mq < 4; ++mq) {
          const float4 vv = *(const float4*)&vs[c][16*part + 4*mq];
          const float t0 = fmaf(-sv[4*mq+0], vv.x, 1.0f);
          const float t1 = fmaf(-sv[4*mq+1], vv.y, 1.0f);
          const float t2 = fmaf(-sv[4*mq+2], vv.z, 1.0f);
          const float t3 = fmaf(-sv[4*mq+3], vv.w, 1.0f);
          a = a * ((t0*t1)*(t2*t3));
        }
        Ap[c] = a;
      }
    }
  }
  __syncthreads();
  if (part >= 2) {
    #pragma unroll
    for (int c = 0; c < OC; ++c) ssf[(part-2)*OC + c][cbf] = Ap[c];
  }
  __syncthreads();
  if (part < 2) {
    #pragma unroll
    for (int c = 0; c < OC; ++c) Ap[c] *= ssf[part*OC + c][cbf];
  }
  __syncthreads();
  if (part == 1) {
    #pragma unroll
    for (int c = 0; c < OC; ++c) ssf[c][cbf] = Ap[c];
  }
  __syncthreads();
  if (part == 0) {
    #pragma unroll
    for (int c = 0; c < OC; ++c) Ap[c] *= ssf[c][cbf];
    const float Nv = Ap[NCLS];
    float Ks = Nv;
    #pragma unroll
    for (int c = 0; c < NCLS; ++c) Ks += Ap[c] - Nv;
    const float invk = 1.0f / Ks;
    #pragma unroll
    for (int c = 0; c < NCLS; ++c) ssf[c][cbf] = (Ap[c] - Nv) * invk;
    ssf[NCLS][cbf] = Nv * invk;
  }
  __syncthreads();
  for (int idx = t; idx < TBF*OC; idx += 256) {
    const int b = idx / OC, c = idx - b*OC;
    OUT[(size_t)bbase*OC + idx] = ssf[c][b];
  }
}

extern "C" void kernel_launch(void* const* d_in, const int* in_sizes, int n_in,
                              void* d_out, int out_size, void* d_ws, size_t ws_size,
                              hipStream_t stream) {
  (void)in_sizes; (void)n_in; (void)out_size;
  const float* X     = (const float*)d_in[0];
  const float* Wm    = (const float*)d_in[1];
  const float* BETA  = (const float*)d_in[2];
  const float* ALPHA = (const float*)d_in[3];
  const float* GAMMA = (const float*)d_in[4];
  float* OUT = (float*)d_out;

  if (ws_size < WS_NEED) {   // fallback: verified f32 path
    hipLaunchKernelGGL(evid_fused, dim3(NBATCH/TBF), dim3(256), 0, stream,
                       X, Wm, BETA, ALPHA, GAMMA, OUT);
    return;
  }
  char* ws = (char*)d_ws;
  unsigned short* PWH = (unsigned short*)(ws + OFF_PWH);
  unsigned short* PWL = (unsigned short*)(ws + OFF_PWL);
  float* VS = (float*)(ws + OFF_VS);
  float* WQ = (float*)(ws + OFF_WQ);
  float* AP = (float*)(ws + OFF_AP);
  float* G2 = (float*)(ws + OFF_G2);

  hipLaunchKernelGGL(prep, dim3(66), dim3(256), 0, stream,
                     Wm, BETA, ALPHA, GAMMA, PWH, PWL, WQ, VS, AP, G2);
  hipLaunchKernelGGL(evid_main, dim3(NBATCH/32), dim3(256), 0, stream,
                     X, PWH, PWL, VS, WQ, AP, G2, OUT);
}

// Round 9
// 112.332 us; speedup vs baseline: 1.9988x; 1.9988x over previous
//
#include <hip/hip_runtime.h>
#include <math.h>

// EvidNets fused, MFMA bf16x2, scalar-pipe combine.
//   A_c(b) = prod_k (1 - s_kb * (1 - U_kc)),  N(b) = prod_k (1 - s_kb)
//   out[b][c<20] = (A_c - N)/K,  out[b][20] = N/K,  K = sum_c A_c - 19*N
//   s_kb = alphap_k * exp(-gamma_k^2 * (0.5*(|W_k|^2 + |x_b|^2) - W_k.x_b))
// R7 post-mortem: combine's 84 broadcast b128 LDS reads/chunk/wave saturated
// the CU-shared LDS pipe (~50k cyc/CU). Now: 64-sample waves, k-slice per
// wave, 1-U values are wave-uniform -> s_load into SGPRs (scalar pipe),
// inner loop = v_fma_f32 with SGPR operand. s-tile column-swizzled
// (col=(p+4(b&31))&127), conflict-free, 1 barrier/chunk (dbuf).
// NOTE: plain __launch_bounds__ — (.,2) min-waves caused spill (R4/R5);
// 3 acc chains + heavy prefetch regs caused the 256-VGPR spill (R8).

#define NBATCH 16384
#define ND     256
#define NP     512
#define NCLS   20
#define OC     21

typedef short  short8  __attribute__((ext_vector_type(8)));
typedef short  short4v __attribute__((ext_vector_type(4)));
typedef unsigned short ushort8 __attribute__((ext_vector_type(8)));
typedef float  f32x16  __attribute__((ext_vector_type(16)));

// ---- workspace layout (bytes) ----
#define OFF_PWH 0u
#define OFF_PWL 262144u
#define OFF_VS  524288u                 // float VS[21][512] = 1-U (row 20 = 1)
#define OFF_WQ  (OFF_VS + 43008u)
#define OFF_AP  (OFF_WQ + 2048u)
#define OFF_G2  (OFF_AP + 2048u)
#define WS_NEED ((size_t)(OFF_G2 + 2048u))

__device__ __forceinline__ unsigned short f2bf_rn(float f) {
  unsigned int u = __float_as_uint(f);
  unsigned int r = (u + 0x7FFFu + ((u >> 16) & 1u)) >> 16;   // RNE (finite inputs)
  return (unsigned short)r;
}
__device__ __forceinline__ float bf2f(unsigned short h) {
  return __uint_as_float(((unsigned int)h) << 16);
}

// Combined prep: blocks 0..63 pack W[512][256] -> MFMA B-fragment order hi/lo
// bf16 + row sum-squares; blocks 64..65 build VS/AP/G2 tables.
// frag elem (tile,step,lane,j) = src[tile*32+(lane&31)][step*16+8*(lane>>5)+j]
__global__ __launch_bounds__(256)
void prep(const float* __restrict__ Wsrc, const float* __restrict__ BETA,
          const float* __restrict__ alpha, const float* __restrict__ gamma,
          unsigned short* __restrict__ dh, unsigned short* __restrict__ dl,
          float* __restrict__ sq, float* __restrict__ VS,
          float* __restrict__ AP, float* __restrict__ G2)
{
  const int bid = blockIdx.x;
  if (bid < 64) {                      // ---- pack W ----
    const int tid = bid * 256 + threadIdx.x;
    const int row = tid >> 5, seg = tid & 31;
    const float4* s4 = (const float4*)(Wsrc + (size_t)row * ND + seg * 8);
    const float4 a = s4[0], b = s4[1];
    const float v[8] = {a.x, a.y, a.z, a.w, b.x, b.y, b.z, b.w};
    ushort8 hv, lv;
    float ssq = 0.f;
    #pragma unroll
    for (int j = 0; j < 8; ++j) {
      ssq = fmaf(v[j], v[j], ssq);
      const unsigned short hh = f2bf_rn(v[j]);
      hv[j] = hh;
      lv[j] = f2bf_rn(v[j] - bf2f(hh));
    }
    const int tile = row >> 5, m = row & 31, step = seg >> 1, r = seg & 1;
    const size_t cidx = (size_t)(tile * 16 + step) * 64 + m + 32 * r;
    *(ushort8*)(dh + cidx * 8) = hv;
    *(ushort8*)(dl + cidx * 8) = lv;
    #pragma unroll
    for (int off = 1; off < 32; off <<= 1) ssq += __shfl_xor(ssq, off, 64);
    if (seg == 0) sq[row] = ssq;
  } else {                             // ---- scalar tables ----
    const int k = (bid - 64) * 256 + threadIdx.x;
    if (k >= NP) return;
    float bv[NCLS], bs = 0.f;
    #pragma unroll
    for (int c = 0; c < NCLS; ++c) { bv[c] = BETA[k * NCLS + c]; bs = fmaf(bv[c], bv[c], bs); }
    const float binv = 1.f / bs;
    #pragma unroll
    for (int c = 0; c < NCLS; ++c) VS[c * NP + k] = 1.f - bv[c] * bv[c] * binv;
    VS[NCLS * NP + k] = 1.f;
    AP[k] = 0.99f / (1.f + __expf(-alpha[k]));
    const float g = gamma[k];
    G2[k] = g * g;
  }
}

// Main kernel: 256 blocks x 512 threads, 64 samples/block, 1 block/CU.
// Chunk = 128 protos (4 chunks). GEMM: wave w -> tile (sh=w&1, pg=w>>1):
// samples sh*32..+32 x protos pg*32..+32. Combine: wave w -> k-slice w*16.
__global__ __launch_bounds__(512)
void evid_main(const float* __restrict__ X,
               const unsigned short* __restrict__ PWH, const unsigned short* __restrict__ PWL,
               const float* __restrict__ VS, const float* __restrict__ WQ,
               const float* __restrict__ AP, const float* __restrict__ G2,
               float* __restrict__ OUT)
{
  __shared__ __align__(16) short Ah[16384], Al[16384];   // [sh][step][lane][8]
  __shared__ __align__(16) float sst[2][8192];           // [par][b][col] col swizzled
  __shared__ float xqs[64];

  const int t    = threadIdx.x;
  const int lane = t & 63;
  const int wv   = __builtin_amdgcn_readfirstlane(t >> 6);  // wave 0..7 (scalar)
  const int tile = blockIdx.x;
  const int bbase = tile * 64;
  const int sh = wv & 1, pg = wv >> 1;
  const int pl = lane & 31, h = lane >> 5;

  // ---- B ring for chunk 0 (in flight during X staging) ----
  const short8* bH = (const short8*)PWH + (size_t)pg * 1024 + lane;
  const short8* bL = (const short8*)PWL + (size_t)pg * 1024 + lane;
  short8 wbh[4], wbl[4];
  #pragma unroll
  for (int p = 0; p < 4; ++p) { wbh[p] = bH[p * 64]; wbl[p] = bL[p * 64]; }

  // ---- stage: convert X rows f32 -> hi/lo bf16 fragments in LDS ----
  {
    const int r  = t >> 3;                // sample row 0..63 (8 lanes/row)
    const int sg = t & 7;
    const int rsh = r >> 5, rm = r & 31;
    const float* xrow = X + (size_t)(bbase + r) * ND;
    float ssq = 0.f;
    #pragma unroll
    for (int it = 0; it < 8; ++it) {
      const int c0 = it * 32 + sg * 4;
      const float4 v = *(const float4*)(xrow + c0);
      const float vv[4] = {v.x, v.y, v.z, v.w};
      short4v h4, l4;
      #pragma unroll
      for (int j = 0; j < 4; ++j) {
        ssq = fmaf(vv[j], vv[j], ssq);
        const unsigned short hh = f2bf_rn(vv[j]);
        h4[j] = (short)hh;
        l4[j] = (short)f2bf_rn(vv[j] - bf2f(hh));
      }
      const int step = c0 >> 4, half = (c0 >> 3) & 1, j0 = c0 & 7;
      const int base = (((rsh * 16 + step) * 64) + (rm + 32 * half)) * 8 + j0;
      *(short4v*)&Ah[base] = h4;
      *(short4v*)&Al[base] = l4;
    }
    ssq += __shfl_xor(ssq, 1, 64);
    ssq += __shfl_xor(ssq, 2, 64);
    ssq += __shfl_xor(ssq, 4, 64);
    if (sg == 0) xqs[r] = ssq;
  }
  __syncthreads();                      // Ah/Al/xqs final

  // preload this lane's 16 xq values (epilogue m-mapping), kill per-chunk LDS
  float xqv[16];
  #pragma unroll
  for (int rg = 0; rg < 16; ++rg)
    xqv[rg] = xqs[sh * 32 + (rg & 3) + 8 * (rg >> 2) + 4 * h];

  float Apc[OC];
  #pragma unroll
  for (int c = 0; c < OC; ++c) Apc[c] = 1.0f;

  #pragma unroll 1
  for (int chunk = 0; chunk < 4; ++chunk) {
    const int par = chunk & 1;
    float* sp = &sst[par][0];

    // per-lane prototype params (L2-resident, coalesced)
    const int kp = chunk * 128 + pg * 32 + pl;
    const float wqk = WQ[kp], apk = AP[kp], g2k = G2[kp];

    // ---- MFMA: 32x32 tile, K=256, 3 independent chains (hh, hl, lh) ----
    f32x16 accA, accB, accC;
    #pragma unroll
    for (int i = 0; i < 16; ++i) { accA[i] = 0.f; accB[i] = 0.f; accC[i] = 0.f; }
    const short8* aH = (const short8*)Ah + (size_t)sh * 1024 + lane;
    const short8* aL = (const short8*)Al + (size_t)sh * 1024 + lane;
    #pragma unroll
    for (int step = 0; step < 16; ++step) {
      const short8 ah = aH[step * 64], al = aL[step * 64];
      const short8 bh = wbh[step & 3], bl = wbl[step & 3];
      if (step < 12) {
        wbh[step & 3] = bH[(step + 4) * 64];
        wbl[step & 3] = bL[(step + 4) * 64];
      }
      accA = __builtin_amdgcn_mfma_f32_32x32x16_bf16(ah, bh, accA, 0, 0, 0);
      accB = __builtin_amdgcn_mfma_f32_32x32x16_bf16(ah, bl, accB, 0, 0, 0);
      accC = __builtin_amdgcn_mfma_f32_32x32x16_bf16(al, bh, accC, 0, 0, 0);
    }

    // ---- epilogue: s = apk*exp(-g2*(0.5*(wq+xq)-dot)), swizzled write ----
    // C/D: col(n)=pl (proto), row(m)=(rg&3)+8*(rg>>2)+4*h. Store col=(p+4m)&127.
    #pragma unroll
    for (int rg = 0; rg < 16; ++rg) {
      const int   m  = (rg & 3) + 8 * (rg >> 2) + 4 * h;
      const int   b  = sh * 32 + m;
      const int   col = (pg * 32 + pl + 4 * m) & 127;
      const float dv = 0.5f * (wqk + xqv[rg]) - (accA[rg] + accB[rg] + accC[rg]);
      sp[b * 128 + col] = apk * __expf(-g2k * dv);
    }

    // prefetch next chunk's B ring (latency covered by barrier + combine)
    if (chunk < 3) {
      bH += 4096; bL += 4096;
      #pragma unroll
      for (int p = 0; p < 4; ++p) { wbh[p] = bH[p * 64]; wbl[p] = bL[p * 64]; }
    }

    __syncthreads();                   // sst[par] complete (the 1 barrier/chunk)

    // ---- combine: lane = sample b (64), wave k-slice = wv*16..+16 ----
    {
      const int kl = wv * 16;          // scalar
      float sv[16];
      #pragma unroll
      for (int q = 0; q < 4; ++q) {
        const int col = (kl + 4 * (lane & 31) + 4 * q) & 127;
        *(float4*)&sv[4 * q] = *(const float4*)&sp[lane * 128 + col];
      }
      const float* vtab = VS + chunk * 128 + kl;   // uniform -> s_load
      for (int c = 0; c < OC; ++c) {
        const float* vp = vtab + (size_t)c * NP;
        float f[16];
        #pragma unroll
        for (int j = 0; j < 16; ++j) f[j] = fmaf(-sv[j], vp[j], 1.0f);
        const float p0 = (f[0] * f[1]) * (f[2] * f[3]);
        const float p1 = (f[4] * f[5]) * (f[6] * f[7]);
        const float p2 = (f[8] * f[9]) * (f[10] * f[11]);
        const float p3 = (f[12] * f[13]) * (f[14] * f[15]);
        Apc[c] *= (p0 * p1) * (p2 * p3);
      }
    }
  }

  // ---- endgame: 8 wave-partials per (b,c), reduce, normalize, store ----
  __syncthreads();                     // all combines (reads of sst) done
  float* S = &sst[0][0];               // 16384 floats scratch
  #pragma unroll
  for (int c = 0; c < OC; ++c) S[(wv * OC + c) * 64 + lane] = Apc[c];
  __syncthreads();
  float* R  = S + 11008;
  {
    const int b = t & 63, j = t >> 6;
    for (int c = j; c < OC; c += 8) {
      float p = S[c * 64 + b];
      #pragma unroll
      for (int w = 1; w < 8; ++w) p *= S[(w * OC + c) * 64 + b];
      R[c * 64 + b] = p;
    }
  }
  __syncthreads();
  float* kv = R + 1344;
  if (t < 64) {
    const float Nv = R[NCLS * 64 + t];
    float K = Nv;
    #pragma unroll
    for (int c = 0; c < NCLS; ++c) K += R[c * 64 + t] - Nv;
    kv[t] = 1.0f / K;
  }
  __syncthreads();
  for (int idx = t; idx < 64 * OC; idx += 512) {
    const int b = idx / OC, c = idx - b * OC;
    const float Nv = R[NCLS * 64 + b];
    const float ik = kv[b];
    OUT[(size_t)tile * 64 * OC + idx] = (c < NCLS) ? (R[c * 64 + b] - Nv) * ik : Nv * ik;
  }
}

// ---------------- fallback (verified f32 path, used if ws too small) ----------------
#define TBF 64
#define TKF 64
#define DSL 64
#define LDX 68

__device__ __forceinline__ void fma4(const float4 a, const float4 b, float& d) {
  d = fmaf(a.x, b.x, d); d = fmaf(a.y, b.y, d);
  d = fmaf(a.z, b.z, d); d = fmaf(a.w, b.w, d);
}

__global__ __launch_bounds__(256)
void evid_fused(const float* __restrict__ X, const float* __restrict__ Wm,
                const float* __restrict__ BETA, const float* __restrict__ ALPHA,
                const float* __restrict__ GAMMA, float* __restrict__ OUT)
{
  __shared__ __align__(16) float xs[DSL][LDX], wsh[DSL][LDX], ssf[TKF][LDX], vs[OC][LDX];
  __shared__ float xq[TBF], wq[TKF], apch[TKF], g2ch[TKF];
  __shared__ float redx[4][TBF], redw[4][TKF];
  const int t = threadIdx.x, bbase = blockIdx.x * TBF;
  const int tb = t & 15, tk = t >> 4, srow = t >> 4, sdq = t & 15;
  const int cbf = t & 63, part = t >> 6;
  float Ap[OC];
  #pragma unroll
  for (int c = 0; c < OC; ++c) Ap[c] = 1.0f;
  float xqacc = 0.0f;
  for (int chunk = 0; chunk < 8; ++chunk) {
    const int k0 = chunk * TKF;
    __syncthreads();
    if (t < TKF) {
      const int k = k0 + t;
      float bsum = 0.0f;
      #pragma unroll
      for (int c = 0; c < NCLS; ++c) { const float bv = BETA[k*NCLS+c]; bsum = fmaf(bv, bv, bsum); }
      const float binv = 1.0f / bsum;
      #pragma unroll
      for (int c = 0; c < NCLS; ++c) { const float bv = BETA[k*NCLS+c]; vs[c][t] = 1.0f - bv*bv*binv; }
      vs[NCLS][t] = 1.0f;
      apch[t] = 0.99f / (1.0f + expf(-ALPHA[k]));
      const float gv = GAMMA[k]; g2ch[t] = gv * gv;
    }
    float acc[4][4] = {};
    float wqacc = 0.0f;
    for (int sl = 0; sl < 4; ++sl) {
      const int d0 = sl * DSL;
      __syncthreads();
      #pragma unroll
      for (int p = 0; p < 4; ++p) {
        const int r = srow + 16 * p;
        *(float4*)&xs [r][4*sdq] = *(const float4*)&X [(size_t)(bbase + r)*ND + d0 + 4*sdq];
        *(float4*)&wsh[r][4*sdq] = *(const float4*)&Wm[(size_t)(k0    + r)*ND + d0 + 4*sdq];
      }
      __syncthreads();
      #pragma unroll
      for (int m = 0; m < 4; ++m) {
        const float4 v = *(const float4*)&wsh[cbf][part*16 + 4*m];
        wqacc = fmaf(v.x,v.x, fmaf(v.y,v.y, fmaf(v.z,v.z, fmaf(v.w,v.w, wqacc))));
      }
      if (chunk == 0) {
        #pragma unroll
        for (int m = 0; m < 4; ++m) {
          const float4 v = *(const float4*)&xs[cbf][part*16 + 4*m];
          xqacc = fmaf(v.x,v.x, fmaf(v.y,v.y, fmaf(v.z,v.z, fmaf(v.w,v.w, xqacc))));
        }
      }
      #pragma unroll
      for (int dq = 0; dq < 16; ++dq) {
        const float4 xa0 = *(const float4*)&xs [tb +  0][4*dq];
        const float4 xa1 = *(const float4*)&xs [tb + 16][4*dq];
        const float4 xa2 = *(const float4*)&xs [tb + 32][4*dq];
        const float4 xa3 = *(const float4*)&xs [tb + 48][4*dq];
        const float4 wb0 = *(const float4*)&wsh[tk +  0][4*dq];
        const float4 wb1 = *(const float4*)&wsh[tk + 16][4*dq];
        const float4 wb2 = *(const float4*)&wsh[tk + 32][4*dq];
        const float4 wb3 = *(const float4*)&wsh[tk + 48][4*dq];
        fma4(xa0, wb0, acc[0][0]); fma4(xa0, wb1, acc[0][1]); fma4(xa0, wb2, acc[0][2]); fma4(xa0, wb3, acc[0][3]);
        fma4(xa1, wb0, acc[1][0]); fma4(xa1, wb1, acc[1][1]); fma4(xa1, wb2, acc[1][2]); fma4(xa1, wb3, acc[1][3]);
        fma4(xa2, wb0, acc[2][0]); fma4(xa2, wb1, acc[2][1]); fma4(xa2, wb2, acc[2][2]); fma4(xa2, wb3, acc[2][3]);
        fma4(xa3, wb0, acc[3][0]); fma4(xa3, wb1, acc[3][1]); fma4(xa3, wb2, acc[3][2]); fma4(xa3, wb3, acc[3][3]);
      }
    }
    redw[part][cbf] = wqacc;
    if (chunk == 0) redx[part][cbf] = xqacc;
    __syncthreads();
    if (t < TKF) {
      wq[t] = redw[0][t] + redw[1][t] + redw[2][t] + redw[3][t];
      if (chunk == 0) xq[t] = redx[0][t] + redx[1][t] + redx[2][t] + redx[3][t];
    }
    __syncthreads();
    #pragma unroll
    for (int j = 0; j < 4; ++j) {
      const int kj = tk + 16 * j;
      const float wqk = wq[kj], ap = apch[kj], g2 = g2ch[kj];
      #pragma unroll
      for (int i = 0; i < 4; ++i) {
        const int bi = tb + 16 * i;
        ssf[kj][bi] = ap * expf(-g2 * (0.5f*(wqk + xq[bi]) - acc[i][j]));
      }
    }
    __syncthreads();
    {
      float sv[16];
      #pragma unroll
      for (int m = 0; m < 16; ++m) sv[m] = ssf[16*part + m][cbf];
      #pragma unroll
      for (int c = 0; c < OC; ++c) {
        float a = Ap[c];
        #pragma unroll
        for (int mq = 0; mq < 4; ++mq) {
          const float4 vv = *(const float4*)&vs[c][16*part + 4*mq];
          const float t0 = fmaf(-sv[4*mq+0], vv.x, 1.0f);
          const float t1 = fmaf(-sv[4*mq+1], vv.y, 1.0f);
          const float t2 = fmaf(-sv[4*mq+2], vv.z, 1.0f);
          const float t3 = fmaf(-sv[4*mq+3], vv.w, 1.0f);
          a = a * ((t0*t1)*(t2*t3));
        }
        Ap[c] = a;
      }
    }
  }
  __syncthreads();
  if (part >= 2) {
    #pragma unroll
    for (int c = 0; c < OC; ++c) ssf[(part-2)*OC + c][cbf] = Ap[c];
  }
  __syncthreads();
  if (part < 2) {
    #pragma unroll
    for (int c = 0; c < OC; ++c) Ap[c] *= ssf[part*OC + c][cbf];
  }
  __syncthreads();
  if (part == 1) {
    #pragma unroll
    for (int c = 0; c < OC; ++c) ssf[c][cbf] = Ap[c];
  }
  __syncthreads();
  if (part == 0) {
    #pragma unroll
    for (int c = 0; c < OC; ++c) Ap[c] *= ssf[c][cbf];
    const float Nv = Ap[NCLS];
    float Ks = Nv;
    #pragma unroll
    for (int c = 0; c < NCLS; ++c) Ks += Ap[c] - Nv;
    const float invk = 1.0f / Ks;
    #pragma unroll
    for (int c = 0; c < NCLS; ++c) ssf[c][cbf] = (Ap[c] - Nv) * invk;
    ssf[NCLS][cbf] = Nv * invk;
  }
  __syncthreads();
  for (int idx = t; idx < TBF*OC; idx += 256) {
    const int b = idx / OC, c = idx - b*OC;
    OUT[(size_t)bbase*OC + idx] = ssf[c][b];
  }
}

extern "C" void kernel_launch(void* const* d_in, const int* in_sizes, int n_in,
                              void* d_out, int out_size, void* d_ws, size_t ws_size,
                              hipStream_t stream) {
  (void)in_sizes; (void)n_in; (void)out_size;
  const float* X     = (const float*)d_in[0];
  const float* Wm    = (const float*)d_in[1];
  const float* BETA  = (const float*)d_in[2];
  const float* ALPHA = (const float*)d_in[3];
  const float* GAMMA = (const float*)d_in[4];
  float* OUT = (float*)d_out;

  if (ws_size < WS_NEED) {   // fallback: verified f32 path
    hipLaunchKernelGGL(evid_fused, dim3(NBATCH/TBF), dim3(256), 0, stream,
                       X, Wm, BETA, ALPHA, GAMMA, OUT);
    return;
  }
  char* ws = (char*)d_ws;
  unsigned short* PWH = (unsigned short*)(ws + OFF_PWH);
  unsigned short* PWL = (unsigned short*)(ws + OFF_PWL);
  float* VS = (float*)(ws + OFF_VS);
  float* WQ = (float*)(ws + OFF_WQ);
  float* AP = (float*)(ws + OFF_AP);
  float* G2 = (float*)(ws + OFF_G2);

  hipLaunchKernelGGL(prep, dim3(66), dim3(256), 0, stream,
                     Wm, BETA, ALPHA, GAMMA, PWH, PWL, WQ, VS, AP, G2);
  hipLaunchKernelGGL(evid_main, dim3(NBATCH/64), dim3(512), 0, stream,
                     X, PWH, PWL, VS, WQ, AP, G2, OUT);
}

// Round 10
// 111.918 us; speedup vs baseline: 2.0062x; 1.0037x over previous
//
#include <hip/hip_runtime.h>
#include <math.h>

// EvidNets, two-kernel split.
//   A_c(b) = prod_k (1 - s_kb*(1-U_kc)),  N(b) = prod_k (1 - s_kb)
//   out[b][c<20] = (A_c-N)/K, out[b][20] = N/K, K = sum_c A_c - 19N
//   s_kb = alphap_k * exp(-gamma_k^2*(0.5*(|W_k|^2+|x_b|^2) - W_k.x_b))
// R9 post-mortem: fused kernel is pinned at 2 waves/SIMD by the 64KB A-tile
// + s-tile LDS; all latency exposed. Split: gemm_s (32KB LDS, 4 waves/SIMD,
// coalesced blocked-S store straight from MFMA regs) + combine (lane=sample,
// wave-uniform 1-U via s_load, one pass). S = 32MB f32 in d_ws.
// NOTE: plain __launch_bounds__ — min-waves args caused scratch spills (R4/R8).

#define NBATCH 16384
#define ND     256
#define NP     512
#define NCLS   20
#define OC     21

typedef short  short8  __attribute__((ext_vector_type(8)));
typedef short  short4v __attribute__((ext_vector_type(4)));
typedef unsigned short ushort8 __attribute__((ext_vector_type(8)));
typedef float  f32x16  __attribute__((ext_vector_type(16)));

// ---- workspace layout (bytes) ----
#define OFF_PWH 0u
#define OFF_PWL 262144u
#define OFF_VS  524288u                 // float VS[21][512] = 1-U (row 20 = 1)
#define OFF_WQ  567296u
#define OFF_AP  569344u
#define OFF_G2  571392u
#define WS_SMALL 573440u
#define OFF_SG  1048576u                // float S blocked [512][32][512] = 32 MB
#define WS_BIG  ((size_t)(OFF_SG + 33554432u))

__device__ __forceinline__ unsigned short f2bf_rn(float f) {
  unsigned int u = __float_as_uint(f);
  unsigned int r = (u + 0x7FFFu + ((u >> 16) & 1u)) >> 16;   // RNE (finite inputs)
  return (unsigned short)r;
}
__device__ __forceinline__ float bf2f(unsigned short h) {
  return __uint_as_float(((unsigned int)h) << 16);
}

// Combined prep: blocks 0..63 pack W[512][256] -> MFMA B-fragment order hi/lo
// bf16 + row sum-squares; blocks 64..65 build VS/AP/G2 tables.
// frag elem (tile,step,lane,j) = src[tile*32+(lane&31)][step*16+8*(lane>>5)+j]
__global__ __launch_bounds__(256)
void prep(const float* __restrict__ Wsrc, const float* __restrict__ BETA,
          const float* __restrict__ alpha, const float* __restrict__ gamma,
          unsigned short* __restrict__ dh, unsigned short* __restrict__ dl,
          float* __restrict__ sq, float* __restrict__ VS,
          float* __restrict__ AP, float* __restrict__ G2)
{
  const int bid = blockIdx.x;
  if (bid < 64) {                      // ---- pack W ----
    const int tid = bid * 256 + threadIdx.x;
    const int row = tid >> 5, seg = tid & 31;
    const float4* s4 = (const float4*)(Wsrc + (size_t)row * ND + seg * 8);
    const float4 a = s4[0], b = s4[1];
    const float v[8] = {a.x, a.y, a.z, a.w, b.x, b.y, b.z, b.w};
    ushort8 hv, lv;
    float ssq = 0.f;
    #pragma unroll
    for (int j = 0; j < 8; ++j) {
      ssq = fmaf(v[j], v[j], ssq);
      const unsigned short hh = f2bf_rn(v[j]);
      hv[j] = hh;
      lv[j] = f2bf_rn(v[j] - bf2f(hh));
    }
    const int tile = row >> 5, m = row & 31, step = seg >> 1, r = seg & 1;
    const size_t cidx = (size_t)(tile * 16 + step) * 64 + m + 32 * r;
    *(ushort8*)(dh + cidx * 8) = hv;
    *(ushort8*)(dl + cidx * 8) = lv;
    #pragma unroll
    for (int off = 1; off < 32; off <<= 1) ssq += __shfl_xor(ssq, off, 64);
    if (seg == 0) sq[row] = ssq;
  } else {                             // ---- scalar tables ----
    const int k = (bid - 64) * 256 + threadIdx.x;
    if (k >= NP) return;
    float bv[NCLS], bs = 0.f;
    #pragma unroll
    for (int c = 0; c < NCLS; ++c) { bv[c] = BETA[k * NCLS + c]; bs = fmaf(bv[c], bv[c], bs); }
    const float binv = 1.f / bs;
    #pragma unroll
    for (int c = 0; c < NCLS; ++c) VS[c * NP + k] = 1.f - bv[c] * bv[c] * binv;
    VS[NCLS * NP + k] = 1.f;
    AP[k] = 0.99f / (1.f + __expf(-alpha[k]));
    const float g = gamma[k];
    G2[k] = g * g;
  }
}

// ---- Kernel A: 512 blocks x 512 thr, 32 samples, 8 proto-group waves,
// 2 chunks of 256 protos. Writes s to blocked SG[btile][m][k], coalesced. ----
__global__ __launch_bounds__(512)
void gemm_s(const float* __restrict__ X,
            const unsigned short* __restrict__ PWH, const unsigned short* __restrict__ PWL,
            const float* __restrict__ WQ, const float* __restrict__ AP,
            const float* __restrict__ G2, float* __restrict__ SG)
{
  __shared__ __align__(16) short Ah[8192], Al[8192];   // A-frags (step*64+lane)*8
  __shared__ float xqs[32];

  const int t    = threadIdx.x;
  const int lane = t & 63;
  const int wv   = __builtin_amdgcn_readfirstlane(t >> 6);  // proto group 0..7
  const int tile = blockIdx.x;
  const int bbase = tile * 32;
  const int pl = lane & 31, h = lane >> 5;

  // B ring for chunk 0 (in flight during X staging); ptile = chunk*8 + wv
  const short8* bH = (const short8*)PWH + (size_t)wv * 1024 + lane;
  const short8* bL = (const short8*)PWL + (size_t)wv * 1024 + lane;
  short8 wbh[4], wbl[4];
  #pragma unroll
  for (int p = 0; p < 4; ++p) { wbh[p] = bH[p * 64]; wbl[p] = bL[p * 64]; }

  // ---- stage: X rows f32 -> hi/lo bf16 fragments (32 rows, 16 lanes/row) ----
  {
    const int r  = t >> 4;
    const int sg = t & 15;
    const float* xrow = X + (size_t)(bbase + r) * ND;
    float ssq = 0.f;
    #pragma unroll
    for (int it = 0; it < 4; ++it) {
      const int c0 = it * 64 + sg * 4;
      const float4 v = *(const float4*)(xrow + c0);
      const float vv[4] = {v.x, v.y, v.z, v.w};
      short4v h4, l4;
      #pragma unroll
      for (int j = 0; j < 4; ++j) {
        ssq = fmaf(vv[j], vv[j], ssq);
        const unsigned short hh = f2bf_rn(vv[j]);
        h4[j] = (short)hh;
        l4[j] = (short)f2bf_rn(vv[j] - bf2f(hh));
      }
      const int step = c0 >> 4, half = (c0 >> 3) & 1, j0 = c0 & 7;
      const int base = (step * 64 + (r + 32 * half)) * 8 + j0;
      *(short4v*)&Ah[base] = h4;
      *(short4v*)&Al[base] = l4;
    }
    ssq += __shfl_xor(ssq, 1, 64);
    ssq += __shfl_xor(ssq, 2, 64);
    ssq += __shfl_xor(ssq, 4, 64);
    ssq += __shfl_xor(ssq, 8, 64);
    if (sg == 0) xqs[r] = ssq;
  }
  __syncthreads();                      // the only barrier

  float xqv[16];
  #pragma unroll
  for (int rg = 0; rg < 16; ++rg)
    xqv[rg] = xqs[(rg & 3) + 8 * (rg >> 2) + 4 * h];

  #pragma unroll 1
  for (int chunk = 0; chunk < 2; ++chunk) {
    const int kp = chunk * 256 + wv * 32 + pl;
    const float wqk = WQ[kp], apk = AP[kp], g2k = G2[kp];

    // MFMA: 32x32 tile, K=256, 3 independent chains (hh, hl, lh)
    f32x16 accA, accB, accC;
    #pragma unroll
    for (int i = 0; i < 16; ++i) { accA[i] = 0.f; accB[i] = 0.f; accC[i] = 0.f; }
    const short8* aH = (const short8*)Ah + lane;
    const short8* aL = (const short8*)Al + lane;
    #pragma unroll
    for (int step = 0; step < 16; ++step) {
      const short8 ah = aH[step * 64], al = aL[step * 64];
      const short8 bh = wbh[step & 3], bl = wbl[step & 3];
      if (step < 12) {
        wbh[step & 3] = bH[(step + 4) * 64];
        wbl[step & 3] = bL[(step + 4) * 64];
      }
      accA = __builtin_amdgcn_mfma_f32_32x32x16_bf16(ah, bh, accA, 0, 0, 0);
      accB = __builtin_amdgcn_mfma_f32_32x32x16_bf16(ah, bl, accB, 0, 0, 0);
      accC = __builtin_amdgcn_mfma_f32_32x32x16_bf16(al, bh, accC, 0, 0, 0);
    }
    if (chunk < 1) {                   // prefetch chunk-1 B ring
      bH += 8192; bL += 8192;
      #pragma unroll
      for (int p = 0; p < 4; ++p) { wbh[p] = bH[p * 64]; wbl[p] = bL[p * 64]; }
    }

    // epilogue: s = apk*exp(-g2*(0.5*(wq+xq)-dot)); store coalesced:
    // C/D: col(n)=pl (proto), row(m)=(rg&3)+8*(rg>>2)+4h.
    // SG addr = tile*16384 + m*512 + kp : lanes -> consecutive k.
    float* sgb = SG + (size_t)tile * 16384 + kp;
    #pragma unroll
    for (int rg = 0; rg < 16; ++rg) {
      const int   m  = (rg & 3) + 8 * (rg >> 2) + 4 * h;
      const float dv = 0.5f * (wqk + xqv[rg]) - (accA[rg] + accB[rg] + accC[rg]);
      sgb[m * 512] = apk * __expf(-g2k * dv);
    }
  }
}

// ---- Kernel B: 256 blocks x 512 thr. lane = sample (64/block), wave = 64-k
// slice. Single pass: stream S rows, 1-U via wave-uniform s_load, endgame. ----
__global__ __launch_bounds__(512)
void combine(const float* __restrict__ SG, const float* __restrict__ VS,
             float* __restrict__ OUT)
{
  __shared__ float S[12160];            // 8*21*64 partials + 1344 R + 64 kv

  const int t    = threadIdx.x;
  const int lane = t & 63;
  const int wv   = __builtin_amdgcn_readfirstlane(t >> 6);  // k-slice 0..7
  const int tile = blockIdx.x;
  const int k0   = wv * 64;

  // stream this lane's 64 s values (blocked layout)
  const float* srow = SG + ((size_t)(tile * 2 + (lane >> 5)) * 16384)
                         + (size_t)(lane & 31) * 512 + k0;
  float sv[64];
  #pragma unroll
  for (int q = 0; q < 16; ++q)
    *(float4*)&sv[4 * q] = *(const float4*)(srow + 4 * q);

  float Apc[OC];
  const float* vt = VS + k0;            // wave-uniform -> s_load
  for (int c = 0; c < OC; ++c) {
    const float* vp = vt + (size_t)c * NP;
    float f[64];
    #pragma unroll
    for (int j = 0; j < 64; ++j) f[j] = fmaf(-sv[j], vp[j], 1.0f);
    #pragma unroll
    for (int w = 32; w >= 1; w >>= 1)
      for (int j = 0; j < w; ++j) f[j] *= f[j + w];
    Apc[c] = f[0];
  }

  // endgame: 8 k-slice partials per (b,c) -> product, normalize, store
  #pragma unroll
  for (int c = 0; c < OC; ++c) S[(wv * OC + c) * 64 + lane] = Apc[c];
  __syncthreads();
  float* R = S + 10752;
  {
    const int b = t & 63, j = t >> 6;
    for (int c = j; c < OC; c += 8) {
      float p = S[c * 64 + b];
      #pragma unroll
      for (int w = 1; w < 8; ++w) p *= S[(w * OC + c) * 64 + b];
      R[c * 64 + b] = p;
    }
  }
  __syncthreads();
  float* kv = R + 1344;
  if (t < 64) {
    const float Nv = R[NCLS * 64 + t];
    float K = Nv;
    #pragma unroll
    for (int c = 0; c < NCLS; ++c) K += R[c * 64 + t] - Nv;
    kv[t] = 1.0f / K;
  }
  __syncthreads();
  for (int idx = t; idx < 64 * OC; idx += 512) {
    const int b = idx / OC, c = idx - b * OC;
    const float Nv = R[NCLS * 64 + b];
    OUT[(size_t)tile * 64 * OC + idx] =
        ((c < NCLS) ? (R[c * 64 + b] - Nv) : Nv) * kv[b];
  }
}

// ---------------- fallback: R9 fused kernel (proven, used if ws < WS_BIG) ----------------
__global__ __launch_bounds__(512)
void evid_main(const float* __restrict__ X,
               const unsigned short* __restrict__ PWH, const unsigned short* __restrict__ PWL,
               const float* __restrict__ VS, const float* __restrict__ WQ,
               const float* __restrict__ AP, const float* __restrict__ G2,
               float* __restrict__ OUT)
{
  __shared__ __align__(16) short Ah[16384], Al[16384];
  __shared__ __align__(16) float sst[2][8192];
  __shared__ float xqs[64];

  const int t    = threadIdx.x;
  const int lane = t & 63;
  const int wv   = __builtin_amdgcn_readfirstlane(t >> 6);
  const int tile = blockIdx.x;
  const int bbase = tile * 64;
  const int sh = wv & 1, pg = wv >> 1;
  const int pl = lane & 31, h = lane >> 5;

  const short8* bH = (const short8*)PWH + (size_t)pg * 1024 + lane;
  const short8* bL = (const short8*)PWL + (size_t)pg * 1024 + lane;
  short8 wbh[4], wbl[4];
  #pragma unroll
  for (int p = 0; p < 4; ++p) { wbh[p] = bH[p * 64]; wbl[p] = bL[p * 64]; }

  {
    const int r  = t >> 3;
    const int sg = t & 7;
    const int rsh = r >> 5, rm = r & 31;
    const float* xrow = X + (size_t)(bbase + r) * ND;
    float ssq = 0.f;
    #pragma unroll
    for (int it = 0; it < 8; ++it) {
      const int c0 = it * 32 + sg * 4;
      const float4 v = *(const float4*)(xrow + c0);
      const float vv[4] = {v.x, v.y, v.z, v.w};
      short4v h4, l4;
      #pragma unroll
      for (int j = 0; j < 4; ++j) {
        ssq = fmaf(vv[j], vv[j], ssq);
        const unsigned short hh = f2bf_rn(vv[j]);
        h4[j] = (short)hh;
        l4[j] = (short)f2bf_rn(vv[j] - bf2f(hh));
      }
      const int step = c0 >> 4, half = (c0 >> 3) & 1, j0 = c0 & 7;
      const int base = (((rsh * 16 + step) * 64) + (rm + 32 * half)) * 8 + j0;
      *(short4v*)&Ah[base] = h4;
      *(short4v*)&Al[base] = l4;
    }
    ssq += __shfl_xor(ssq, 1, 64);
    ssq += __shfl_xor(ssq, 2, 64);
    ssq += __shfl_xor(ssq, 4, 64);
    if (sg == 0) xqs[r] = ssq;
  }
  __syncthreads();

  float xqv[16];
  #pragma unroll
  for (int rg = 0; rg < 16; ++rg)
    xqv[rg] = xqs[sh * 32 + (rg & 3) + 8 * (rg >> 2) + 4 * h];

  float Apc[OC];
  #pragma unroll
  for (int c = 0; c < OC; ++c) Apc[c] = 1.0f;

  #pragma unroll 1
  for (int chunk = 0; chunk < 4; ++chunk) {
    const int par = chunk & 1;
    float* sp = &sst[par][0];
    const int kp = chunk * 128 + pg * 32 + pl;
    const float wqk = WQ[kp], apk = AP[kp], g2k = G2[kp];

    f32x16 accA, accB, accC;
    #pragma unroll
    for (int i = 0; i < 16; ++i) { accA[i] = 0.f; accB[i] = 0.f; accC[i] = 0.f; }
    const short8* aH = (const short8*)Ah + (size_t)sh * 1024 + lane;
    const short8* aL = (const short8*)Al + (size_t)sh * 1024 + lane;
    #pragma unroll
    for (int step = 0; step < 16; ++step) {
      const short8 ah = aH[step * 64], al = aL[step * 64];
      const short8 bh = wbh[step & 3], bl = wbl[step & 3];
      if (step < 12) {
        wbh[step & 3] = bH[(step + 4) * 64];
        wbl[step & 3] = bL[(step + 4) * 64];
      }
      accA = __builtin_amdgcn_mfma_f32_32x32x16_bf16(ah, bh, accA, 0, 0, 0);
      accB = __builtin_amdgcn_mfma_f32_32x32x16_bf16(ah, bl, accB, 0, 0, 0);
      accC = __builtin_amdgcn_mfma_f32_32x32x16_bf16(al, bh, accC, 0, 0, 0);
    }

    #pragma unroll
    for (int rg = 0; rg < 16; ++rg) {
      const int   m  = (rg & 3) + 8 * (rg >> 2) + 4 * h;
      const int   b  = sh * 32 + m;
      const int   col = (pg * 32 + pl + 4 * m) & 127;
      const float dv = 0.5f * (wqk + xqv[rg]) - (accA[rg] + accB[rg] + accC[rg]);
      sp[b * 128 + col] = apk * __expf(-g2k * dv);
    }

    if (chunk < 3) {
      bH += 4096; bL += 4096;
      #pragma unroll
      for (int p = 0; p < 4; ++p) { wbh[p] = bH[p * 64]; wbl[p] = bL[p * 64]; }
    }

    __syncthreads();

    {
      const int kl = wv * 16;
      float sv[16];
      #pragma unroll
      for (int q = 0; q < 4; ++q) {
        const int col = (kl + 4 * (lane & 31) + 4 * q) & 127;
        *(float4*)&sv[4 * q] = *(const float4*)&sp[lane * 128 + col];
      }
      const float* vtab = VS + chunk * 128 + kl;
      for (int c = 0; c < OC; ++c) {
        const float* vp = vtab + (size_t)c * NP;
        float f[16];
        #pragma unroll
        for (int j = 0; j < 16; ++j) f[j] = fmaf(-sv[j], vp[j], 1.0f);
        const float p0 = (f[0] * f[1]) * (f[2] * f[3]);
        const float p1 = (f[4] * f[5]) * (f[6] * f[7]);
        const float p2 = (f[8] * f[9]) * (f[10] * f[11]);
        const float p3 = (f[12] * f[13]) * (f[14] * f[15]);
        Apc[c] *= (p0 * p1) * (p2 * p3);
      }
    }
  }

  __syncthreads();
  float* S = &sst[0][0];
  #pragma unroll
  for (int c = 0; c < OC; ++c) S[(wv * OC + c) * 64 + lane] = Apc[c];
  __syncthreads();
  float* R  = S + 11008;
  {
    const int b = t & 63, j = t >> 6;
    for (int c = j; c < OC; c += 8) {
      float p = S[c * 64 + b];
      #pragma unroll
      for (int w = 1; w < 8; ++w) p *= S[(w * OC + c) * 64 + b];
      R[c * 64 + b] = p;
    }
  }
  __syncthreads();
  float* kv = R + 1344;
  if (t < 64) {
    const float Nv = R[NCLS * 64 + t];
    float K = Nv;
    #pragma unroll
    for (int c = 0; c < NCLS; ++c) K += R[c * 64 + t] - Nv;
    kv[t] = 1.0f / K;
  }
  __syncthreads();
  for (int idx = t; idx < 64 * OC; idx += 512) {
    const int b = idx / OC, c = idx - b * OC;
    const float Nv = R[NCLS * 64 + b];
    const float ik = kv[b];
    OUT[(size_t)tile * 64 * OC + idx] = (c < NCLS) ? (R[c * 64 + b] - Nv) * ik : Nv * ik;
  }
}

extern "C" void kernel_launch(void* const* d_in, const int* in_sizes, int n_in,
                              void* d_out, int out_size, void* d_ws, size_t ws_size,
                              hipStream_t stream) {
  (void)in_sizes; (void)n_in; (void)out_size;
  const float* X     = (const float*)d_in[0];
  const float* Wm    = (const float*)d_in[1];
  const float* BETA  = (const float*)d_in[2];
  const float* ALPHA = (const float*)d_in[3];
  const float* GAMMA = (const float*)d_in[4];
  float* OUT = (float*)d_out;

  char* ws = (char*)d_ws;
  unsigned short* PWH = (unsigned short*)(ws + OFF_PWH);
  unsigned short* PWL = (unsigned short*)(ws + OFF_PWL);
  float* VS = (float*)(ws + OFF_VS);
  float* WQ = (float*)(ws + OFF_WQ);
  float* AP = (float*)(ws + OFF_AP);
  float* G2 = (float*)(ws + OFF_G2);

  hipLaunchKernelGGL(prep, dim3(66), dim3(256), 0, stream,
                     Wm, BETA, ALPHA, GAMMA, PWH, PWL, WQ, VS, AP, G2);

  if (ws_size >= WS_BIG) {             // two-kernel path
    float* SG = (float*)(ws + OFF_SG);
    hipLaunchKernelGGL(gemm_s, dim3(NBATCH/32), dim3(512), 0, stream,
                       X, PWH, PWL, WQ, AP, G2, SG);
    hipLaunchKernelGGL(combine, dim3(NBATCH/64), dim3(512), 0, stream,
                       SG, VS, OUT);
  } else {                             // proven fused fallback (R9)
    hipLaunchKernelGGL(evid_main, dim3(NBATCH/64), dim3(512), 0, stream,
                       X, PWH, PWL, VS, WQ, AP, G2, OUT);
  }
}